// Round 7
// baseline (511.722 us; speedup 1.0000x reference)
//
#include <hip/hip_runtime.h>
#include <math.h>

#define NPIX 6272       // B*H*W = 2*56*56
#define LVAL 3136       // H*W
#define CIN 192         // d_inner
#define NST 16          // d_state
#define HW 56

#define KSTEPS 112      // steps per chunk (2 rows)
#define KCH 28          // chunks per chain (= LVAL/KSTEPS)
#define NCHAIN 16       // 8 (d,b) x 2 channel-halves
#define NFLAGS (NCHAIN * KCH)

__device__ __forceinline__ float softplusf(float v) {
    return (v > 20.0f) ? v : log1pf(expf(v));
}

// direction geometry: pixel(l) = off + i*si + j*sj, l = i*56 + j
__device__ __forceinline__ void dir_geom(int d, int b, int& si, int& sj, int& off) {
    if (d == 0)      { si = HW;  sj = 1;   off = b * LVAL; }
    else if (d == 1) { si = HW;  sj = -1;  off = b * LVAL + (HW - 1); }
    else if (d == 2) { si = 1;   sj = HW;  off = b * LVAL; }
    else             { si = -1;  sj = HW;  off = b * LVAL + (HW - 1); }
}

// K1: xz = x @ W_in ; 16 pixels/block, LDS-broadcast x, acc[16]/thread.
__global__ __launch_bounds__(384) void k_inproj(
    const float* __restrict__ x, const float* __restrict__ W_in,
    float* __restrict__ xm, float* __restrict__ z)
{
    __shared__ __align__(16) float xs[96][20];
    const int p0 = blockIdx.x * 16;
    const int t = threadIdx.x;
    for (int e = t; e < 16 * 96; e += 384) {
        int p = e / 96, kk = e % 96;
        xs[kk][p] = x[p0 * 96 + e];
    }
    __syncthreads();
    float acc[16];
#pragma unroll
    for (int p = 0; p < 16; ++p) acc[p] = 0.f;
    for (int k = 0; k < 96; ++k) {
        float w = W_in[k * 384 + t];
        float4 x0 = *(const float4*)&xs[k][0];
        float4 x1 = *(const float4*)&xs[k][4];
        float4 x2 = *(const float4*)&xs[k][8];
        float4 x3 = *(const float4*)&xs[k][12];
        acc[0]  = fmaf(x0.x, w, acc[0]);  acc[1]  = fmaf(x0.y, w, acc[1]);
        acc[2]  = fmaf(x0.z, w, acc[2]);  acc[3]  = fmaf(x0.w, w, acc[3]);
        acc[4]  = fmaf(x1.x, w, acc[4]);  acc[5]  = fmaf(x1.y, w, acc[5]);
        acc[6]  = fmaf(x1.z, w, acc[6]);  acc[7]  = fmaf(x1.w, w, acc[7]);
        acc[8]  = fmaf(x2.x, w, acc[8]);  acc[9]  = fmaf(x2.y, w, acc[9]);
        acc[10] = fmaf(x2.z, w, acc[10]); acc[11] = fmaf(x2.w, w, acc[11]);
        acc[12] = fmaf(x3.x, w, acc[12]); acc[13] = fmaf(x3.y, w, acc[13]);
        acc[14] = fmaf(x3.z, w, acc[14]); acc[15] = fmaf(x3.w, w, acc[15]);
    }
#pragma unroll
    for (int p = 0; p < 16; ++p) {
        int pix = p0 + p;
        if (t < 192) xm[pix * CIN + t] = acc[p];
        else         z[pix * CIN + (t - 192)] = acc[p];
    }
}

// K23: FUSED depthwise-conv + xproj + dt. Block 0 also zeroes the lookback
// flags + ticket (stream-ordered before the scan kernel).
__global__ __launch_bounds__(512) void k_xproj_dt(
    const float* __restrict__ xm, const float* __restrict__ cw,
    const float* __restrict__ cb,
    const float* __restrict__ W_xproj,
    const float* __restrict__ W_dt, const float* __restrict__ b_dt,
    float* __restrict__ Bp, float* __restrict__ Cp, float2* __restrict__ dtx2,
    int* __restrict__ flags_ticket)
{
    __shared__ __align__(16) float xs[192][28];
    __shared__ float part[2][24][40];
    __shared__ float dtr_lds[24][8];
    const int p0 = blockIdx.x * 24;
    const int t = threadIdx.x;
    if (blockIdx.x == 0) {
        for (int e = t; e < NFLAGS + 1; e += 512) flags_ticket[e] = 0;
    }
    for (int e = t; e < 24 * 192; e += 512) {
        int p = e / 192, kk = e % 192;
        int pix = p0 + p;
        float v = 0.f;
        if (pix < NPIX) {
            int w = pix % HW;
            int rest = pix / HW;
            int h = rest % HW;
            int b = rest / HW;
            v = cb[kk];
#pragma unroll
            for (int ky = 0; ky < 3; ++ky) {
                int hh = h + ky - 1;
                if (hh < 0 || hh >= HW) continue;
#pragma unroll
                for (int kx = 0; kx < 3; ++kx) {
                    int ww = w + kx - 1;
                    if (ww < 0 || ww >= HW) continue;
                    v = fmaf(xm[((b * HW + hh) * HW + ww) * CIN + kk],
                             cw[(ky * 3 + kx) * CIN + kk], v);
                }
            }
        }
        xs[kk][p] = v;
    }
    __syncthreads();
    const int th = t & 255;
    const int kh = t >> 8;               // 0..1 -> k range [kh*96, kh*96+96)
    const int j  = th % 40;
    const int pq = th / 40;              // 0..6; pq==6 idle
    if (pq < 6) {
        const int jc = (j < 38) ? j : 37;
        float a0 = 0.f, a1 = 0.f, a2 = 0.f, a3 = 0.f;
        const int k0 = kh * 96;
        for (int k = k0; k < k0 + 96; ++k) {
            float w = W_xproj[k * 38 + jc];
            float4 xv = *(const float4*)&xs[k][pq * 4];
            a0 = fmaf(xv.x, w, a0); a1 = fmaf(xv.y, w, a1);
            a2 = fmaf(xv.z, w, a2); a3 = fmaf(xv.w, w, a3);
        }
        part[kh][pq * 4 + 0][j] = a0;
        part[kh][pq * 4 + 1][j] = a1;
        part[kh][pq * 4 + 2][j] = a2;
        part[kh][pq * 4 + 3][j] = a3;
    }
    __syncthreads();
    if (kh == 0 && pq < 6 && j < 38) {
#pragma unroll
        for (int q = 0; q < 4; ++q) {
            int p = pq * 4 + q;
            float r = part[0][p][j] + part[1][p][j];
            int pix = p0 + p;
            if (j < 6) dtr_lds[p][j] = r;
            if (pix < NPIX) {
                if (j < 6)       ;   // dtr stays in LDS
                else if (j < 22) Bp[pix * NST + (j - 6)] = r;
                else             Cp[pix * NST + (j - 22)] = r;
            }
        }
    }
    __syncthreads();
    // Phase B: dt = softplus(dtr@W_dt + b_dt); pack with x from LDS.
    for (int e = t; e < 24 * 192; e += 512) {
        int p = e / 192, c = e % 192;
        int pix = p0 + p;
        if (pix >= NPIX) continue;
        float v = b_dt[c];
#pragma unroll
        for (int r = 0; r < 6; ++r)
            v = fmaf(dtr_lds[p][r], W_dt[r * CIN + c], v);
        dtx2[(size_t)pix * CIN + c] = make_float2(softplusf(v), xs[c][p]);
    }
}

// R6: single-launch chained-lookback scan.
// 448 blocks (all co-resident: 2688 waves << 8192 cap -> no deadlock possible).
// Each block: sweep1 (local h, P) -> wait pred flag -> publish inclusive carry
// -> sweep2 (y) with h0 = carry_in. Math identical to p1/fix/p2 structure.
__global__ __launch_bounds__(384) void k_scan_lb(
    const float2* __restrict__ dtx2, const float* __restrict__ Bp,
    const float* __restrict__ Cp, const float* __restrict__ A_log,
    const float* __restrict__ D_skip,
    float* __restrict__ carry, int* __restrict__ flags, int* __restrict__ ticket,
    float* __restrict__ Y4)
{
    __shared__ __align__(16) float Bs[KSTEPS * NST];   // 7 KB
    __shared__ __align__(16) float Cs[KSTEPS * NST];   // 7 KB
    __shared__ int vk_s;
    const int t = threadIdx.x;
    if (t == 0) vk_s = atomicAdd(ticket, 1);   // start-ordered virtual block id
    __syncthreads();
    const int vid = vk_s;
    const int chain = vid & (NCHAIN - 1);      // 0..15
    const int myk   = vid >> 4;                // 0..27 (chunk along chain)
    const int g  = chain >> 1;                 // (d,b)
    const int ch = chain & 1;                  // channel half
    const int wv = t >> 6, lane = t & 63;
    const int cl = lane & 15, nh = lane >> 4;  // 16 ch x 4 n-groups
    const int c    = ch * 96 + wv * 16 + cl;
    const int cloc = wv * 16 + cl;             // 0..95
    const int n0 = nh * 4;
    const int d = g >> 1, b = g & 1;
    int si, sj, off;
    dir_geom(d, b, si, sj, off);
    const int r0 = myk * 2;                    // first of 2 rows in this chunk

    // stage B,C for 112 steps: step jj -> row r0 + (jj>=56), col jj%56
    for (int e = t; e < KSTEPS * NST; e += 384) {
        int jj = e >> 4, n = e & 15;
        int rr = (jj >= 56) ? 1 : 0;
        int j  = jj - rr * 56;
        int pix = off + (r0 + rr) * si + j * sj;
        Bs[e] = Bp[pix * NST + n];
        Cs[e] = Cp[pix * NST + n];
    }

    const float LOG2E = 1.4426950408889634f;
    float a2[4];
    {
        float4 v = *(const float4*)(A_log + c * NST + n0);
        a2[0] = -expf(v.x) * LOG2E;
        a2[1] = -expf(v.y) * LOG2E;
        a2[2] = -expf(v.z) * LOG2E;
        a2[3] = -expf(v.w) * LOG2E;
    }
    __syncthreads();

    const ptrdiff_t dstep = (ptrdiff_t)sj * CIN;

    // ---- sweep 1: local scan (carry-in = 0) ----
    float h[4] = {0.f, 0.f, 0.f, 0.f};
    float Sdt = 0.f;
    for (int rr = 0; rr < 2; ++rr) {
        const float2* dp = dtx2 + (size_t)(off + (r0 + rr) * si) * CIN + c;
        const float* Brow = Bs + rr * 56 * NST;
#pragma unroll 4
        for (int j2 = 0; j2 < 56; ++j2) {
            float2 dv = dp[(ptrdiff_t)j2 * dstep];
            float dt_c = dv.x, x_c = dv.y;
            float dtx = dt_c * x_c;
            Sdt += dt_c;
            float4 bq = *(const float4*)(Brow + j2 * NST + n0);
            float Bv[4] = {bq.x, bq.y, bq.z, bq.w};
#pragma unroll
            for (int i = 0; i < 4; ++i) {
                float dA = exp2f(dt_c * a2[i]);
                h[i] = fmaf(dA, h[i], dtx * Bv[i]);
            }
        }
    }
    float P[4];
#pragma unroll
    for (int i = 0; i < 4; ++i) P[i] = exp2f(a2[i] * Sdt);

    // ---- lookback: receive carry, publish inclusive ----
    const int slot = chain * KCH + myk;
    float cin[4] = {0.f, 0.f, 0.f, 0.f};
    if (myk > 0) {
        if (t == 0) {
            long long spins = 0;
            while (__hip_atomic_load(&flags[slot - 1], __ATOMIC_ACQUIRE,
                                     __HIP_MEMORY_SCOPE_AGENT) == 0) {
                if (++spins > 200000000LL) break;   // bailout: fail loud, not hang
            }
        }
        __syncthreads();
        const float* cp = carry + (size_t)(slot - 1) * 1536 + cloc * NST + n0;
#pragma unroll
        for (int i = 0; i < 4; ++i)
            cin[i] = __hip_atomic_load(cp + i, __ATOMIC_RELAXED,
                                       __HIP_MEMORY_SCOPE_AGENT);
    }
    if (myk < KCH - 1) {
        float* co = carry + (size_t)slot * 1536 + cloc * NST + n0;
#pragma unroll
        for (int i = 0; i < 4; ++i) {
            float inc = fmaf(P[i], cin[i], h[i]);   // same recurrence as k_scan_fix
            __hip_atomic_store(co + i, inc, __ATOMIC_RELAXED,
                               __HIP_MEMORY_SCOPE_AGENT);
        }
        __syncthreads();           // all waves' stores drained (vmcnt) at barrier
        if (t == 0) {
            __threadfence();
            __hip_atomic_store(&flags[slot], 1, __ATOMIC_RELEASE,
                               __HIP_MEMORY_SCOPE_AGENT);
        }
    }

    // ---- sweep 2: rescan with carry, emit y ----
    const float Dc = D_skip[c];
#pragma unroll
    for (int i = 0; i < 4; ++i) h[i] = cin[i];
    for (int rr = 0; rr < 2; ++rr) {
        const float2* dp = dtx2 + (size_t)(off + (r0 + rr) * si) * CIN + c;
        const float* Brow = Bs + rr * 56 * NST;
        const float* Crow = Cs + rr * 56 * NST;
        float* yo = Y4 + ((size_t)d * NPIX + (size_t)b * LVAL
                          + (size_t)(r0 + rr) * 56) * CIN;
#pragma unroll 4
        for (int j2 = 0; j2 < 56; ++j2) {
            float2 dv = dp[(ptrdiff_t)j2 * dstep];
            float dt_c = dv.x, x_c = dv.y;
            float dtx = dt_c * x_c;
            float4 bq = *(const float4*)(Brow + j2 * NST + n0);
            float4 uq = *(const float4*)(Crow + j2 * NST + n0);
            float Bv[4] = {bq.x, bq.y, bq.z, bq.w};
            float Cv[4] = {uq.x, uq.y, uq.z, uq.w};
            float yc0 = 0.f, yc1 = 0.f;
#pragma unroll
            for (int i = 0; i < 4; i += 2) {
                float dA0 = exp2f(dt_c * a2[i]);
                float dA1 = exp2f(dt_c * a2[i+1]);
                h[i]   = fmaf(dA0, h[i],   dtx * Bv[i]);
                h[i+1] = fmaf(dA1, h[i+1], dtx * Bv[i+1]);
                yc0 = fmaf(h[i],   Cv[i],   yc0);
                yc1 = fmaf(h[i+1], Cv[i+1], yc1);
            }
            float yc = yc0 + yc1;
            yc += __shfl_xor(yc, 16, 64);
            yc += __shfl_xor(yc, 32, 64);
            if (nh == 0)
                yo[j2 * CIN + c] = fmaf(Dc, x_c, yc);
        }
    }
}

// K5: fused gate + outproj. 16 pixels/block, 384 threads, acc[4]/thread.
__global__ __launch_bounds__(384) void k_gateout(
    const float* __restrict__ Y4, const float* __restrict__ z,
    const float* __restrict__ W_out, float* __restrict__ out)
{
    __shared__ __align__(16) float xs[192][20];
    const int p0 = blockIdx.x * 16;
    const int t = threadIdx.x;
    const size_t NP = (size_t)NPIX * CIN;
    for (int e = t; e < 16 * 192; e += 384) {
        int p = e / 192, c = e % 192;
        size_t idx = (size_t)(p0 + p) * CIN + c;
        float s = Y4[idx] + Y4[idx + NP] + Y4[idx + 2 * NP] + Y4[idx + 3 * NP];
        float zz = z[idx];
        float sig = 1.f / (1.f + expf(-zz));
        xs[c][p] = zz * sig * s;
    }
    __syncthreads();
    const int j  = t % 96;
    const int ph = t / 96;          // 0..3 -> pixels ph*4 .. ph*4+3
    float acc[4] = {0.f, 0.f, 0.f, 0.f};
    for (int k = 0; k < 192; ++k) {
        float w = W_out[k * 96 + j];
        float4 xv = *(const float4*)&xs[k][ph * 4];
        acc[0] = fmaf(xv.x, w, acc[0]); acc[1] = fmaf(xv.y, w, acc[1]);
        acc[2] = fmaf(xv.z, w, acc[2]); acc[3] = fmaf(xv.w, w, acc[3]);
    }
#pragma unroll
    for (int p = 0; p < 4; ++p)
        out[(p0 + ph * 4 + p) * 96 + j] = acc[p];
}

extern "C" void kernel_launch(void* const* d_in, const int* in_sizes, int n_in,
                              void* d_out, int out_size, void* d_ws, size_t ws_size,
                              hipStream_t stream) {
    const float* x      = (const float*)d_in[0];
    const float* W_in   = (const float*)d_in[1];
    const float* conv_w = (const float*)d_in[2];
    const float* conv_b = (const float*)d_in[3];
    const float* W_xproj= (const float*)d_in[4];
    const float* W_dt   = (const float*)d_in[5];
    const float* b_dt   = (const float*)d_in[6];
    const float* A_log  = (const float*)d_in[7];
    const float* D_skip = (const float*)d_in[8];
    const float* W_out  = (const float*)d_in[9];
    float* out = (float*)d_out;

    float* ws   = (float*)d_ws;
    float* xm   = ws;                        // [NPIX*CIN]
    float* z    = xm  + NPIX * CIN;          // [NPIX*CIN]
    float* xcv  = z   + NPIX * CIN;          // (kept for layout stability; unused)
    float2* dtx2= (float2*)(xcv + NPIX * CIN); // [NPIX*CIN] float2
    float* Bp   = (float*)(dtx2 + (size_t)NPIX * CIN); // [NPIX*NST]
    float* Cp   = Bp  + NPIX * NST;          // [NPIX*NST]
    float* Y4   = Cp  + NPIX * NST;          // [4*NPIX*CIN]
    float* carry= Y4  + (size_t)4 * NPIX * CIN;        // [16*28*1536] = 2.75 MB
    int*  flags = (int*)(carry + (size_t)NCHAIN * KCH * 1536); // [448]
    int*  ticket= flags + NFLAGS;                       // [1]

    k_inproj  <<<NPIX / 16, 384, 0, stream>>>(x, W_in, xm, z);
    k_xproj_dt<<<(NPIX + 23) / 24, 512, 0, stream>>>(xm, conv_w, conv_b,
                                                     W_xproj, W_dt, b_dt,
                                                     Bp, Cp, dtx2, flags);
    k_scan_lb <<<NCHAIN * KCH, 384, 0, stream>>>(dtx2, Bp, Cp, A_log, D_skip,
                                                 carry, flags, ticket, Y4);
    k_gateout <<<NPIX / 16, 384, 0, stream>>>(Y4, z, W_out, out);
}

// Round 8
// 217.529 us; speedup vs baseline: 2.3524x; 2.3524x over previous
//
#include <hip/hip_runtime.h>
#include <math.h>

#define NPIX 6272       // B*H*W = 2*56*56
#define LVAL 3136       // H*W
#define CIN 192         // d_inner
#define NST 16          // d_state
#define HW 56
#define CHUNK28 28
#define NCH 112         // LVAL / CHUNK28

__device__ __forceinline__ float softplusf(float v) {
    return (v > 20.0f) ? v : log1pf(expf(v));
}

// direction geometry: pixel(l) = off + i*si + j*sj, l = i*56 + j
__device__ __forceinline__ void dir_geom(int d, int b, int& si, int& sj, int& off) {
    if (d == 0)      { si = HW;  sj = 1;   off = b * LVAL; }
    else if (d == 1) { si = HW;  sj = -1;  off = b * LVAL + (HW - 1); }
    else if (d == 2) { si = 1;   sj = HW;  off = b * LVAL; }
    else             { si = -1;  sj = HW;  off = b * LVAL + (HW - 1); }
}

// K1: xz = x @ W_in ; 16 pixels/block, LDS-broadcast x, acc[16]/thread.
__global__ __launch_bounds__(384) void k_inproj(
    const float* __restrict__ x, const float* __restrict__ W_in,
    float* __restrict__ xm, float* __restrict__ z)
{
    __shared__ __align__(16) float xs[96][20];
    const int p0 = blockIdx.x * 16;
    const int t = threadIdx.x;
    for (int e = t; e < 16 * 96; e += 384) {
        int p = e / 96, kk = e % 96;
        xs[kk][p] = x[p0 * 96 + e];
    }
    __syncthreads();
    float acc[16];
#pragma unroll
    for (int p = 0; p < 16; ++p) acc[p] = 0.f;
    for (int k = 0; k < 96; ++k) {
        float w = W_in[k * 384 + t];
        float4 x0 = *(const float4*)&xs[k][0];
        float4 x1 = *(const float4*)&xs[k][4];
        float4 x2 = *(const float4*)&xs[k][8];
        float4 x3 = *(const float4*)&xs[k][12];
        acc[0]  = fmaf(x0.x, w, acc[0]);  acc[1]  = fmaf(x0.y, w, acc[1]);
        acc[2]  = fmaf(x0.z, w, acc[2]);  acc[3]  = fmaf(x0.w, w, acc[3]);
        acc[4]  = fmaf(x1.x, w, acc[4]);  acc[5]  = fmaf(x1.y, w, acc[5]);
        acc[6]  = fmaf(x1.z, w, acc[6]);  acc[7]  = fmaf(x1.w, w, acc[7]);
        acc[8]  = fmaf(x2.x, w, acc[8]);  acc[9]  = fmaf(x2.y, w, acc[9]);
        acc[10] = fmaf(x2.z, w, acc[10]); acc[11] = fmaf(x2.w, w, acc[11]);
        acc[12] = fmaf(x3.x, w, acc[12]); acc[13] = fmaf(x3.y, w, acc[13]);
        acc[14] = fmaf(x3.z, w, acc[14]); acc[15] = fmaf(x3.w, w, acc[15]);
    }
#pragma unroll
    for (int p = 0; p < 16; ++p) {
        int pix = p0 + p;
        if (t < 192) xm[pix * CIN + t] = acc[p];
        else         z[pix * CIN + (t - 192)] = acc[p];
    }
}

// K23: FUSED depthwise-conv + xproj + dt (verified R5/R6).
__global__ __launch_bounds__(512) void k_xproj_dt(
    const float* __restrict__ xm, const float* __restrict__ cw,
    const float* __restrict__ cb,
    const float* __restrict__ W_xproj,
    const float* __restrict__ W_dt, const float* __restrict__ b_dt,
    float* __restrict__ Bp, float* __restrict__ Cp, float2* __restrict__ dtx2)
{
    __shared__ __align__(16) float xs[192][28];
    __shared__ float part[2][24][40];
    __shared__ float dtr_lds[24][8];
    const int p0 = blockIdx.x * 24;
    const int t = threadIdx.x;
    for (int e = t; e < 24 * 192; e += 512) {
        int p = e / 192, kk = e % 192;
        int pix = p0 + p;
        float v = 0.f;
        if (pix < NPIX) {
            int w = pix % HW;
            int rest = pix / HW;
            int h = rest % HW;
            int b = rest / HW;
            v = cb[kk];
#pragma unroll
            for (int ky = 0; ky < 3; ++ky) {
                int hh = h + ky - 1;
                if (hh < 0 || hh >= HW) continue;
#pragma unroll
                for (int kx = 0; kx < 3; ++kx) {
                    int ww = w + kx - 1;
                    if (ww < 0 || ww >= HW) continue;
                    v = fmaf(xm[((b * HW + hh) * HW + ww) * CIN + kk],
                             cw[(ky * 3 + kx) * CIN + kk], v);
                }
            }
        }
        xs[kk][p] = v;
    }
    __syncthreads();
    const int th = t & 255;
    const int kh = t >> 8;               // 0..1 -> k range [kh*96, kh*96+96)
    const int j  = th % 40;
    const int pq = th / 40;              // 0..6; pq==6 idle
    if (pq < 6) {
        const int jc = (j < 38) ? j : 37;
        float a0 = 0.f, a1 = 0.f, a2 = 0.f, a3 = 0.f;
        const int k0 = kh * 96;
        for (int k = k0; k < k0 + 96; ++k) {
            float w = W_xproj[k * 38 + jc];
            float4 xv = *(const float4*)&xs[k][pq * 4];
            a0 = fmaf(xv.x, w, a0); a1 = fmaf(xv.y, w, a1);
            a2 = fmaf(xv.z, w, a2); a3 = fmaf(xv.w, w, a3);
        }
        part[kh][pq * 4 + 0][j] = a0;
        part[kh][pq * 4 + 1][j] = a1;
        part[kh][pq * 4 + 2][j] = a2;
        part[kh][pq * 4 + 3][j] = a3;
    }
    __syncthreads();
    if (kh == 0 && pq < 6 && j < 38) {
#pragma unroll
        for (int q = 0; q < 4; ++q) {
            int p = pq * 4 + q;
            float r = part[0][p][j] + part[1][p][j];
            int pix = p0 + p;
            if (j < 6) dtr_lds[p][j] = r;
            if (pix < NPIX) {
                if (j < 6)       ;   // dtr stays in LDS
                else if (j < 22) Bp[pix * NST + (j - 6)] = r;
                else             Cp[pix * NST + (j - 22)] = r;
            }
        }
    }
    __syncthreads();
    // Phase B: dt = softplus(dtr@W_dt + b_dt); pack with x from LDS.
    for (int e = t; e < 24 * 192; e += 512) {
        int p = e / 192, c = e % 192;
        int pix = p0 + p;
        if (pix >= NPIX) continue;
        float v = b_dt[c];
#pragma unroll
        for (int r = 0; r < 6; ++r)
            v = fmaf(dtr_lds[p][r], W_dt[r * CIN + c], v);
        dtx2[(size_t)pix * CIN + c] = make_float2(softplusf(v), xs[c][p]);
    }
}

// R7: k_scan_y — ONE sweep replaces old p1+p2's two sweeps.
// Computes y_local (h0=0) into Y4, running S_l (= sum dt) into Sbuf, and
// chunk summaries (P = exp2(a2*Sdt), h_end) into Pbuf/qbuf for k_scan_fix.
// Geometry: R2 trio (grid (112,8,2), 384 thr, 4-way n-split).
__global__ __launch_bounds__(384) void k_scan_y(
    const float2* __restrict__ dtx2, const float* __restrict__ Bp,
    const float* __restrict__ Cp, const float* __restrict__ A_log,
    const float* __restrict__ D_skip,
    float* __restrict__ Pbuf, float* __restrict__ qbuf,
    float* __restrict__ Sbuf, float* __restrict__ Y4)
{
    constexpr int CPR = HW / CHUNK28;   // 2
    __shared__ __align__(16) float Bs[CHUNK28 * NST];
    __shared__ __align__(16) float Cs[CHUNK28 * NST];
    const int g = blockIdx.y;
    const int k = blockIdx.x;
    const int ch = blockIdx.z;
    const int t = threadIdx.x;
    const int wv = t >> 6;
    const int lane = t & 63;
    const int cl = lane & 15, nh = lane >> 4;
    const int c = ch * 96 + wv * 16 + cl;
    const int n0 = nh * 4;
    const int d = g >> 1, b = g & 1;
    int si, sj, off;
    dir_geom(d, b, si, sj, off);
    const int base = off + (k / CPR) * si + ((k % CPR) * CHUNK28) * sj;

    for (int e = t; e < CHUNK28 * NST; e += 384) {
        int jj = e >> 4, n = e & 15;
        int pa = (base + jj * sj) * NST + n;
        Bs[e] = Bp[pa];
        Cs[e] = Cp[pa];
    }

    const float LOG2E = 1.4426950408889634f;
    float a2[4];
    {
        float4 v = *(const float4*)(A_log + c * NST + n0);
        a2[0] = -expf(v.x) * LOG2E;
        a2[1] = -expf(v.y) * LOG2E;
        a2[2] = -expf(v.z) * LOG2E;
        a2[3] = -expf(v.w) * LOG2E;
    }
    const float Dc = D_skip[c];
    __syncthreads();

    float* yo = Y4   + ((size_t)g * LVAL + (size_t)k * CHUNK28) * CIN;
    float* So = Sbuf + ((size_t)g * LVAL + (size_t)k * CHUNK28) * CIN;

    const float2* dp = dtx2 + (size_t)base * CIN + c;
    const ptrdiff_t dstep = (ptrdiff_t)sj * CIN;

    float h[4] = {0.f, 0.f, 0.f, 0.f};
    float Sdt = 0.f;
    float2 dv = dp[0];
    for (int jj = 0; jj < CHUNK28; ++jj) {
        float dt_c = dv.x, x_c = dv.y;
        int jn = (jj + 1 < CHUNK28) ? jj + 1 : jj;
        dv = dp[(ptrdiff_t)jn * dstep];
        float dtx = dt_c * x_c;
        Sdt += dt_c;
        float4 t0 = *(const float4*)(Bs + jj * NST + n0);
        float4 u0 = *(const float4*)(Cs + jj * NST + n0);
        float yc = 0.f;
#pragma unroll
        for (int i = 0; i < 4; ++i) {
            float dA = exp2f(dt_c * a2[i]);
            h[i] = fmaf(dA, h[i], (&t0.x)[i] * dtx);
            yc = fmaf(h[i], (&u0.x)[i], yc);
        }
        yc += __shfl_xor(yc, 16, 64);
        yc += __shfl_xor(yc, 32, 64);
        if (nh == 0) {
            yo[jj * CIN + c] = fmaf(Dc, x_c, yc);
            So[jj * CIN + c] = Sdt;          // inclusive prefix of dt
        }
    }

    float4* Pd = (float4*)(Pbuf + ((size_t)(k * 8 + g) * CIN + c) * NST + n0);
    float4* qd = (float4*)(qbuf + ((size_t)(k * 8 + g) * CIN + c) * NST + n0);
    Pd[0] = make_float4(exp2f(a2[0]*Sdt), exp2f(a2[1]*Sdt),
                        exp2f(a2[2]*Sdt), exp2f(a2[3]*Sdt));
    qd[0] = make_float4(h[0], h[1], h[2], h[3]);
}

// K4b: sequential chunk combine (unchanged). qbuf becomes EXCLUSIVE carries.
__global__ __launch_bounds__(256) void k_scan_fix(
    const float* __restrict__ Pbuf, float* __restrict__ qbuf, int nch)
{
    const int g = blockIdx.y;
    const int lo = blockIdx.x * 256 + threadIdx.x;
    const size_t stride = (size_t)8 * CIN * NST;
    size_t idx  = (size_t)g * CIN * NST + lo;
    size_t pidx = idx;
    float Pr[8], qr[8];
#pragma unroll
    for (int i = 0; i < 8; ++i) { Pr[i] = Pbuf[pidx]; qr[i] = qbuf[pidx]; pidx += stride; }
    float h = 0.f;
    for (int k = 0; k < nch; k += 8) {
        float Pn[8], qn[8];
        if (k + 8 < nch) {
#pragma unroll
            for (int i = 0; i < 8; ++i) {
                Pn[i] = Pbuf[pidx + (size_t)i * stride];
                qn[i] = qbuf[pidx + (size_t)i * stride];
            }
        } else {
#pragma unroll
            for (int i = 0; i < 8; ++i) { Pn[i] = 0.f; qn[i] = 0.f; }
        }
#pragma unroll
        for (int i = 0; i < 8; ++i) {
            qbuf[idx] = h;
            h = fmaf(Pr[i], h, qr[i]);
            idx += stride;
        }
#pragma unroll
        for (int i = 0; i < 8; ++i) { Pr[i] = Pn[i]; qr[i] = qn[i]; }
        pidx += (size_t)8 * stride;
    }
}

// R7: k_scan_corr — fully parallel carry correction (no rescan).
// y_l += sum_n C_l[n] * exp2(a2[n]*S_l) * carry[n].  One block per (chunk,g);
// thread owns one channel (carry+a2 in 32 regs), loops 14 pixels.
__global__ __launch_bounds__(384) void k_scan_corr(
    const float* __restrict__ qbuf,      // exclusive carries
    const float* __restrict__ Cp, const float* __restrict__ A_log,
    const float* __restrict__ Sbuf, float* __restrict__ Y4)
{
    __shared__ __align__(16) float qs[CIN * NST];    // 12 KB
    __shared__ __align__(16) float as[CIN * NST];    // 12 KB
    __shared__ __align__(16) float cs[CHUNK28 * NST]; // 1.8 KB
    const int k = blockIdx.x;        // chunk 0..111
    const int g = blockIdx.y;        // 0..7
    const int t = threadIdx.x;
    const float LOG2E = 1.4426950408889634f;
    const size_t qbase = (size_t)(k * 8 + g) * CIN * NST;
    for (int e = t; e < CIN * NST; e += 384) {
        qs[e] = qbuf[qbase + e];
        as[e] = -expf(A_log[e]) * LOG2E;
    }
    {
        const int d = g >> 1, b = g & 1;
        int si, sj, off; dir_geom(d, b, si, sj, off);
        for (int e = t; e < CHUNK28 * NST; e += 384) {
            int jl = e >> 4, n = e & 15;
            int l = k * CHUNK28 + jl;
            int i = l / 56, j = l % 56;
            int pix = off + i * si + j * sj;
            cs[e] = Cp[pix * NST + n];
        }
    }
    __syncthreads();
    const int c  = t % 192;
    const int jh = t / 192;          // 0..1 -> pixels jh*14 .. +13
    float4 qv[4], av[4];
#pragma unroll
    for (int q = 0; q < 4; ++q) {
        qv[q] = *(const float4*)(qs + c * NST + q * 4);
        av[q] = *(const float4*)(as + c * NST + q * 4);
    }
    const size_t fb = ((size_t)g * LVAL + (size_t)k * CHUNK28) * CIN + c;
#pragma unroll
    for (int m = 0; m < 14; ++m) {
        const int jl = jh * 14 + m;
        const size_t flat = fb + (size_t)jl * CIN;
        float S = Sbuf[flat];
        float y = Y4[flat];
        float corr = 0.f;
#pragma unroll
        for (int q = 0; q < 4; ++q) {
            float4 cv = *(const float4*)(cs + jl * NST + q * 4);
            corr = fmaf(cv.x * qv[q].x, exp2f(av[q].x * S), corr);
            corr = fmaf(cv.y * qv[q].y, exp2f(av[q].y * S), corr);
            corr = fmaf(cv.z * qv[q].z, exp2f(av[q].z * S), corr);
            corr = fmaf(cv.w * qv[q].w, exp2f(av[q].w * S), corr);
        }
        Y4[flat] = y + corr;
    }
}

// K5: fused gate + outproj. 16 pixels/block, 384 threads, acc[4]/thread.
__global__ __launch_bounds__(384) void k_gateout(
    const float* __restrict__ Y4, const float* __restrict__ z,
    const float* __restrict__ W_out, float* __restrict__ out)
{
    __shared__ __align__(16) float xs[192][20];
    const int p0 = blockIdx.x * 16;
    const int t = threadIdx.x;
    const size_t NP = (size_t)NPIX * CIN;
    for (int e = t; e < 16 * 192; e += 384) {
        int p = e / 192, c = e % 192;
        size_t idx = (size_t)(p0 + p) * CIN + c;
        float s = Y4[idx] + Y4[idx + NP] + Y4[idx + 2 * NP] + Y4[idx + 3 * NP];
        float zz = z[idx];
        float sig = 1.f / (1.f + expf(-zz));
        xs[c][p] = zz * sig * s;
    }
    __syncthreads();
    const int j  = t % 96;
    const int ph = t / 96;          // 0..3 -> pixels ph*4 .. ph*4+3
    float acc[4] = {0.f, 0.f, 0.f, 0.f};
    for (int k = 0; k < 192; ++k) {
        float w = W_out[k * 96 + j];
        float4 xv = *(const float4*)&xs[k][ph * 4];
        acc[0] = fmaf(xv.x, w, acc[0]); acc[1] = fmaf(xv.y, w, acc[1]);
        acc[2] = fmaf(xv.z, w, acc[2]); acc[3] = fmaf(xv.w, w, acc[3]);
    }
#pragma unroll
    for (int p = 0; p < 4; ++p)
        out[(p0 + ph * 4 + p) * 96 + j] = acc[p];
}

extern "C" void kernel_launch(void* const* d_in, const int* in_sizes, int n_in,
                              void* d_out, int out_size, void* d_ws, size_t ws_size,
                              hipStream_t stream) {
    const float* x      = (const float*)d_in[0];
    const float* W_in   = (const float*)d_in[1];
    const float* conv_w = (const float*)d_in[2];
    const float* conv_b = (const float*)d_in[3];
    const float* W_xproj= (const float*)d_in[4];
    const float* W_dt   = (const float*)d_in[5];
    const float* b_dt   = (const float*)d_in[6];
    const float* A_log  = (const float*)d_in[7];
    const float* D_skip = (const float*)d_in[8];
    const float* W_out  = (const float*)d_in[9];
    float* out = (float*)d_out;

    float* ws   = (float*)d_ws;
    float* xm   = ws;                        // [NPIX*CIN]
    float* z    = xm  + NPIX * CIN;          // [NPIX*CIN]
    float* xcv  = z   + NPIX * CIN;          // (dead; kept for layout stability)
    float2* dtx2= (float2*)(xcv + NPIX * CIN); // [NPIX*CIN] float2
    float* Bp   = (float*)(dtx2 + (size_t)NPIX * CIN); // [NPIX*NST]
    float* Cp   = Bp  + NPIX * NST;          // [NPIX*NST]
    float* Y4   = Cp  + NPIX * NST;          // [4*NPIX*CIN] (seq layout, g-major)
    float* Pbuf = Y4  + (size_t)4 * NPIX * CIN;          // [112*8*CIN*NST]
    float* qbuf = Pbuf + (size_t)NCH * 8 * CIN * NST;    // [112*8*CIN*NST]
    float* Sbuf = qbuf + (size_t)NCH * 8 * CIN * NST;    // [4*NPIX*CIN]
    // total ~21.4M floats = 85.4 MB (<< ws)

    k_inproj  <<<NPIX / 16, 384, 0, stream>>>(x, W_in, xm, z);
    k_xproj_dt<<<(NPIX + 23) / 24, 512, 0, stream>>>(xm, conv_w, conv_b,
                                                     W_xproj, W_dt, b_dt, Bp, Cp, dtx2);
    k_scan_y   <<<dim3(NCH, 8, 2), 384, 0, stream>>>(dtx2, Bp, Cp, A_log, D_skip,
                                                     Pbuf, qbuf, Sbuf, Y4);
    k_scan_fix <<<dim3(12, 8), 256, 0, stream>>>(Pbuf, qbuf, NCH);
    k_scan_corr<<<dim3(NCH, 8), 384, 0, stream>>>(qbuf, Cp, A_log, Sbuf, Y4);
    k_gateout  <<<NPIX / 16, 384, 0, stream>>>(Y4, z, W_out, out);
}

// Round 9
// 211.746 us; speedup vs baseline: 2.4167x; 1.0273x over previous
//
#include <hip/hip_runtime.h>
#include <math.h>

#define NPIX 6272       // B*H*W = 2*56*56
#define LVAL 3136       // H*W
#define CIN 192         // d_inner
#define NST 16          // d_state
#define HW 56
#define CHUNK 28
#define NCH 112         // LVAL / CHUNK

__device__ __forceinline__ float softplusf(float v) {
    return (v > 20.0f) ? v : log1pf(expf(v));
}

// direction geometry: pixel(l) = off + i*si + j*sj, l = i*56 + j
__device__ __forceinline__ void dir_geom(int d, int b, int& si, int& sj, int& off) {
    if (d == 0)      { si = HW;  sj = 1;   off = b * LVAL; }
    else if (d == 1) { si = HW;  sj = -1;  off = b * LVAL + (HW - 1); }
    else if (d == 2) { si = 1;   sj = HW;  off = b * LVAL; }
    else             { si = -1;  sj = HW;  off = b * LVAL + (HW - 1); }
}

// K1: xz = x @ W_in ; 16 pixels/block, LDS-broadcast x, acc[16]/thread.
__global__ __launch_bounds__(384) void k_inproj(
    const float* __restrict__ x, const float* __restrict__ W_in,
    float* __restrict__ xm, float* __restrict__ z)
{
    __shared__ __align__(16) float xs[96][20];
    const int p0 = blockIdx.x * 16;
    const int t = threadIdx.x;
    for (int e = t; e < 16 * 96; e += 384) {
        int p = e / 96, kk = e % 96;
        xs[kk][p] = x[p0 * 96 + e];
    }
    __syncthreads();
    float acc[16];
#pragma unroll
    for (int p = 0; p < 16; ++p) acc[p] = 0.f;
    for (int k = 0; k < 96; ++k) {
        float w = W_in[k * 384 + t];
        float4 x0 = *(const float4*)&xs[k][0];
        float4 x1 = *(const float4*)&xs[k][4];
        float4 x2 = *(const float4*)&xs[k][8];
        float4 x3 = *(const float4*)&xs[k][12];
        acc[0]  = fmaf(x0.x, w, acc[0]);  acc[1]  = fmaf(x0.y, w, acc[1]);
        acc[2]  = fmaf(x0.z, w, acc[2]);  acc[3]  = fmaf(x0.w, w, acc[3]);
        acc[4]  = fmaf(x1.x, w, acc[4]);  acc[5]  = fmaf(x1.y, w, acc[5]);
        acc[6]  = fmaf(x1.z, w, acc[6]);  acc[7]  = fmaf(x1.w, w, acc[7]);
        acc[8]  = fmaf(x2.x, w, acc[8]);  acc[9]  = fmaf(x2.y, w, acc[9]);
        acc[10] = fmaf(x2.z, w, acc[10]); acc[11] = fmaf(x2.w, w, acc[11]);
        acc[12] = fmaf(x3.x, w, acc[12]); acc[13] = fmaf(x3.w ? x3.x : x3.x, 0.f, acc[13]);
        // (restored below — keep exact original arithmetic)
        acc[13] = fmaf(x3.y, w, acc[13]);
        acc[14] = fmaf(x3.z, w, acc[14]); acc[15] = fmaf(x3.w, w, acc[15]);
    }
#pragma unroll
    for (int p = 0; p < 16; ++p) {
        int pix = p0 + p;
        if (t < 192) xm[pix * CIN + t] = acc[p];
        else         z[pix * CIN + (t - 192)] = acc[p];
    }
}

// K23: FUSED depthwise-conv + xproj + dt (verified R5/R6/R8 runs).
__global__ __launch_bounds__(512) void k_xproj_dt(
    const float* __restrict__ xm, const float* __restrict__ cw,
    const float* __restrict__ cb,
    const float* __restrict__ W_xproj,
    const float* __restrict__ W_dt, const float* __restrict__ b_dt,
    float* __restrict__ Bp, float* __restrict__ Cp, float2* __restrict__ dtx2)
{
    __shared__ __align__(16) float xs[192][28];
    __shared__ float part[2][24][40];
    __shared__ float dtr_lds[24][8];
    const int p0 = blockIdx.x * 24;
    const int t = threadIdx.x;
    for (int e = t; e < 24 * 192; e += 512) {
        int p = e / 192, kk = e % 192;
        int pix = p0 + p;
        float v = 0.f;
        if (pix < NPIX) {
            int w = pix % HW;
            int rest = pix / HW;
            int h = rest % HW;
            int b = rest / HW;
            v = cb[kk];
#pragma unroll
            for (int ky = 0; ky < 3; ++ky) {
                int hh = h + ky - 1;
                if (hh < 0 || hh >= HW) continue;
#pragma unroll
                for (int kx = 0; kx < 3; ++kx) {
                    int ww = w + kx - 1;
                    if (ww < 0 || ww >= HW) continue;
                    v = fmaf(xm[((b * HW + hh) * HW + ww) * CIN + kk],
                             cw[(ky * 3 + kx) * CIN + kk], v);
                }
            }
        }
        xs[kk][p] = v;
    }
    __syncthreads();
    const int th = t & 255;
    const int kh = t >> 8;               // 0..1 -> k range [kh*96, kh*96+96)
    const int j  = th % 40;
    const int pq = th / 40;              // 0..6; pq==6 idle
    if (pq < 6) {
        const int jc = (j < 38) ? j : 37;
        float a0 = 0.f, a1 = 0.f, a2 = 0.f, a3 = 0.f;
        const int k0 = kh * 96;
        for (int k = k0; k < k0 + 96; ++k) {
            float w = W_xproj[k * 38 + jc];
            float4 xv = *(const float4*)&xs[k][pq * 4];
            a0 = fmaf(xv.x, w, a0); a1 = fmaf(xv.y, w, a1);
            a2 = fmaf(xv.z, w, a2); a3 = fmaf(xv.w, w, a3);
        }
        part[kh][pq * 4 + 0][j] = a0;
        part[kh][pq * 4 + 1][j] = a1;
        part[kh][pq * 4 + 2][j] = a2;
        part[kh][pq * 4 + 3][j] = a3;
    }
    __syncthreads();
    if (kh == 0 && pq < 6 && j < 38) {
#pragma unroll
        for (int q = 0; q < 4; ++q) {
            int p = pq * 4 + q;
            float r = part[0][p][j] + part[1][p][j];
            int pix = p0 + p;
            if (j < 6) dtr_lds[p][j] = r;
            if (pix < NPIX) {
                if (j < 6)       ;   // dtr stays in LDS
                else if (j < 22) Bp[pix * NST + (j - 6)] = r;
                else             Cp[pix * NST + (j - 22)] = r;
            }
        }
    }
    __syncthreads();
    // Phase B: dt = softplus(dtr@W_dt + b_dt); pack with x from LDS.
    for (int e = t; e < 24 * 192; e += 512) {
        int p = e / 192, c = e % 192;
        int pix = p0 + p;
        if (pix >= NPIX) continue;
        float v = b_dt[c];
#pragma unroll
        for (int r = 0; r < 6; ++r)
            v = fmaf(dtr_lds[p][r], W_dt[r * CIN + c], v);
        dtx2[(size_t)pix * CIN + c] = make_float2(softplusf(v), xs[c][p]);
    }
}

// K4a pass1 — R2 geometry (4-way n-split, grid (112,8,2)).
// R8 change: store Sdt (1 float/chunk/g/c, 172 KB) instead of P (11 MB);
// k_scan_fix recomputes P = exp2(a2*Sdt) with the identical formula ->
// bit-identical results, ~21 MB less traffic.
__global__ __launch_bounds__(384) void k_scan_p1(
    const float2* __restrict__ dtx2, const float* __restrict__ Bp,
    const float* __restrict__ A_log,
    float* __restrict__ Sd, float* __restrict__ qbuf)
{
    constexpr int CPR = HW / CHUNK;
    __shared__ __align__(16) float Bs[CHUNK * NST];
    const int g = blockIdx.y;
    const int k = blockIdx.x;
    const int ch = blockIdx.z;           // channel half: [ch*96, ch*96+96)
    const int t = threadIdx.x;
    const int wv = t >> 6;
    const int lane = t & 63;
    const int cl = lane & 15, nh = lane >> 4;   // 16 channels x 4 n-groups
    const int c = ch * 96 + wv * 16 + cl;
    const int n0 = nh * 4;
    const int d = g >> 1, b = g & 1;
    int si, sj, off;
    dir_geom(d, b, si, sj, off);
    const int base = off + (k / CPR) * si + ((k % CPR) * CHUNK) * sj;

    for (int e = t; e < CHUNK * NST; e += 384) {
        int jj = e >> 4, n = e & 15;
        Bs[e] = Bp[(base + jj * sj) * NST + n];
    }

    const float LOG2E = 1.4426950408889634f;
    float a2[4];
    {
        float4 v = *(const float4*)(A_log + c * NST + n0);
        a2[0] = -expf(v.x) * LOG2E;
        a2[1] = -expf(v.y) * LOG2E;
        a2[2] = -expf(v.z) * LOG2E;
        a2[3] = -expf(v.w) * LOG2E;
    }
    __syncthreads();

    float h[4];
#pragma unroll
    for (int i = 0; i < 4; ++i) h[i] = 0.f;
    float Sdt = 0.f;

    const float2* dp = dtx2 + (size_t)base * CIN + c;
    const ptrdiff_t dstep = (ptrdiff_t)sj * CIN;

#define P1_STEP(DVV, JJ) do {                                            \
        float dt_c = (DVV).x, x_c = (DVV).y;                             \
        float dtx = dt_c * x_c;                                          \
        Sdt += dt_c;                                                     \
        float4 t0 = *(const float4*)(Bs + (JJ) * NST + n0);              \
        float Bv[4] = {t0.x, t0.y, t0.z, t0.w};                          \
        _Pragma("unroll")                                                \
        for (int i = 0; i < 4; ++i) {                                    \
            float dA = exp2f(dt_c * a2[i]);                              \
            h[i] = fmaf(dA, h[i], dtx * Bv[i]);                          \
        }                                                                \
    } while (0)

    float2 v0 = dp[0];
    float2 v1 = dp[dstep];
    float2 v2 = dp[2 * dstep];
    float2 v3 = dp[3 * dstep];
    for (int jj = 0; jj < CHUNK; jj += 4) {
        const int j4 = (jj + 4 < CHUNK) ? jj + 4 : CHUNK - 4;
        float2 nv0 = dp[(ptrdiff_t)(j4 + 0) * dstep];
        float2 nv1 = dp[(ptrdiff_t)(j4 + 1) * dstep];
        float2 nv2 = dp[(ptrdiff_t)(j4 + 2) * dstep];
        float2 nv3 = dp[(ptrdiff_t)(j4 + 3) * dstep];
        P1_STEP(v0, jj + 0);
        P1_STEP(v1, jj + 1);
        P1_STEP(v2, jj + 2);
        P1_STEP(v3, jj + 3);
        v0 = nv0; v1 = nv1; v2 = nv2; v3 = nv3;
    }
#undef P1_STEP

    if (nh == 0)
        Sd[(size_t)(k * 8 + g) * CIN + c] = Sdt;   // shared across n-groups
    float4* qd = (float4*)(qbuf + ((size_t)(k * 8 + g) * CIN + c) * NST + n0);
    qd[0] = make_float4(h[0], h[1], h[2], h[3]);
}

// K4b: sequential chunk combine. P recomputed from Sdt + A_log inline
// (identical -expf(A_log)*LOG2E formula as p1 -> bit-identical P).
__global__ __launch_bounds__(256) void k_scan_fix(
    const float* __restrict__ Sd, const float* __restrict__ A_log,
    float* __restrict__ qbuf, int nch)
{
    const int g = blockIdx.y;
    const int lo = blockIdx.x * 256 + threadIdx.x;   // 0..3071 = c*16+n
    const int c = lo >> 4;
    const float LOG2E = 1.4426950408889634f;
    const float a2t = -expf(A_log[lo]) * LOG2E;
    const size_t stride = (size_t)8 * CIN * NST;
    const size_t sstride = (size_t)8 * CIN;
    size_t idx  = (size_t)g * CIN * NST + lo;
    size_t pidx = idx;
    size_t sidx = (size_t)g * CIN + c;
    float Sv[8], qr[8];
#pragma unroll
    for (int i = 0; i < 8; ++i) {
        Sv[i] = Sd[sidx]; qr[i] = qbuf[pidx];
        sidx += sstride; pidx += stride;
    }
    float h = 0.f;
    for (int k = 0; k < nch; k += 8) {
        float Sn[8], qn[8];
        if (k + 8 < nch) {
#pragma unroll
            for (int i = 0; i < 8; ++i) {
                Sn[i] = Sd[sidx + (size_t)i * sstride];
                qn[i] = qbuf[pidx + (size_t)i * stride];
            }
        } else {
#pragma unroll
            for (int i = 0; i < 8; ++i) { Sn[i] = 0.f; qn[i] = 0.f; }
        }
#pragma unroll
        for (int i = 0; i < 8; ++i) {
            qbuf[idx] = h;
            float P = exp2f(a2t * Sv[i]);
            h = fmaf(P, h, qr[i]);
            idx += stride;
        }
#pragma unroll
        for (int i = 0; i < 8; ++i) { Sv[i] = Sn[i]; qr[i] = qn[i]; }
        sidx += (size_t)8 * sstride;
        pidx += (size_t)8 * stride;
    }
}

// K4c pass2 — R2 exact: 4-way n-split; y via shfl_xor(16)+shfl_xor(32).
__global__ __launch_bounds__(384) void k_scan_p2(
    const float2* __restrict__ dtx2, const float* __restrict__ Bp,
    const float* __restrict__ Cp, const float* __restrict__ A_log,
    const float* __restrict__ D_skip,
    const float* __restrict__ qbuf, float* __restrict__ Y4)
{
    constexpr int CPR = HW / CHUNK;
    __shared__ __align__(16) float Bs[CHUNK * NST];
    __shared__ __align__(16) float Cs[CHUNK * NST];
    const int g = blockIdx.y;
    const int k = blockIdx.x;
    const int ch = blockIdx.z;
    const int t = threadIdx.x;
    const int wv = t >> 6;
    const int lane = t & 63;
    const int cl = lane & 15, nh = lane >> 4;
    const int c = ch * 96 + wv * 16 + cl;
    const int n0 = nh * 4;
    const int d = g >> 1, b = g & 1;
    int si, sj, off;
    dir_geom(d, b, si, sj, off);
    const int base = off + (k / CPR) * si + ((k % CPR) * CHUNK) * sj;

    for (int e = t; e < CHUNK * NST; e += 384) {
        int jj = e >> 4, n = e & 15;
        int pa = (base + jj * sj) * NST + n;
        Bs[e] = Bp[pa];
        Cs[e] = Cp[pa];
    }

    const float LOG2E = 1.4426950408889634f;
    float a2[4];
    {
        float4 v = *(const float4*)(A_log + c * NST + n0);
        a2[0] = -expf(v.x) * LOG2E;
        a2[1] = -expf(v.y) * LOG2E;
        a2[2] = -expf(v.z) * LOG2E;
        a2[3] = -expf(v.w) * LOG2E;
    }
    const float Dc = D_skip[c];

    float h[4];
    {
        float4 v0q = *(const float4*)(qbuf + ((size_t)(k * 8 + g) * CIN + c) * NST + n0);
        h[0]=v0q.x; h[1]=v0q.y; h[2]=v0q.z; h[3]=v0q.w;
    }
    __syncthreads();

    float* yo = Y4 + ((size_t)d * NPIX + (size_t)b * LVAL + (size_t)k * CHUNK) * CIN;

    const float2* dp = dtx2 + (size_t)base * CIN + c;
    const ptrdiff_t dstep = (ptrdiff_t)sj * CIN;

#define P2_STEP(DVV, JJ) do {                                            \
        float dt_c = (DVV).x, x_c = (DVV).y;                             \
        float dtx = dt_c * x_c;                                          \
        float4 t0 = *(const float4*)(Bs + (JJ) * NST + n0);              \
        float4 u0 = *(const float4*)(Cs + (JJ) * NST + n0);              \
        float Bv[4] = {t0.x, t0.y, t0.z, t0.w};                          \
        float Cv[4] = {u0.x, u0.y, u0.z, u0.w};                          \
        float yc0 = 0.f, yc1 = 0.f;                                      \
        _Pragma("unroll")                                                \
        for (int i = 0; i < 4; i += 2) {                                 \
            float dA0 = exp2f(dt_c * a2[i]);                             \
            float dA1 = exp2f(dt_c * a2[i+1]);                           \
            h[i]   = fmaf(dA0, h[i],   dtx * Bv[i]);                     \
            h[i+1] = fmaf(dA1, h[i+1], dtx * Bv[i+1]);                   \
            yc0 = fmaf(h[i],   Cv[i],   yc0);                            \
            yc1 = fmaf(h[i+1], Cv[i+1], yc1);                            \
        }                                                                \
        float yc = yc0 + yc1;                                            \
        yc += __shfl_xor(yc, 16, 64);                                    \
        yc += __shfl_xor(yc, 32, 64);                                    \
        if (nh == 0)                                                     \
            yo[(JJ) * CIN + c] = fmaf(Dc, x_c, yc);                      \
    } while (0)

    float2 v0 = dp[0];
    float2 v1 = dp[dstep];
    float2 v2 = dp[2 * dstep];
    float2 v3 = dp[3 * dstep];
    for (int jj = 0; jj < CHUNK; jj += 4) {
        const int j4 = (jj + 4 < CHUNK) ? jj + 4 : CHUNK - 4;
        float2 nv0 = dp[(ptrdiff_t)(j4 + 0) * dstep];
        float2 nv1 = dp[(ptrdiff_t)(j4 + 1) * dstep];
        float2 nv2 = dp[(ptrdiff_t)(j4 + 2) * dstep];
        float2 nv3 = dp[(ptrdiff_t)(j4 + 3) * dstep];
        P2_STEP(v0, jj + 0);
        P2_STEP(v1, jj + 1);
        P2_STEP(v2, jj + 2);
        P2_STEP(v3, jj + 3);
        v0 = nv0; v1 = nv1; v2 = nv2; v3 = nv3;
    }
#undef P2_STEP
}

// K5: fused gate + outproj. 16 pixels/block, 384 threads, acc[4]/thread.
__global__ __launch_bounds__(384) void k_gateout(
    const float* __restrict__ Y4, const float* __restrict__ z,
    const float* __restrict__ W_out, float* __restrict__ out)
{
    __shared__ __align__(16) float xs[192][20];
    const int p0 = blockIdx.x * 16;
    const int t = threadIdx.x;
    const size_t NP = (size_t)NPIX * CIN;
    for (int e = t; e < 16 * 192; e += 384) {
        int p = e / 192, c = e % 192;
        size_t idx = (size_t)(p0 + p) * CIN + c;
        float s = Y4[idx] + Y4[idx + NP] + Y4[idx + 2 * NP] + Y4[idx + 3 * NP];
        float zz = z[idx];
        float sig = 1.f / (1.f + expf(-zz));
        xs[c][p] = zz * sig * s;
    }
    __syncthreads();
    const int j  = t % 96;
    const int ph = t / 96;          // 0..3 -> pixels ph*4 .. ph*4+3
    float acc[4] = {0.f, 0.f, 0.f, 0.f};
    for (int k = 0; k < 192; ++k) {
        float w = W_out[k * 96 + j];
        float4 xv = *(const float4*)&xs[k][ph * 4];
        acc[0] = fmaf(xv.x, w, acc[0]); acc[1] = fmaf(xv.y, w, acc[1]);
        acc[2] = fmaf(xv.z, w, acc[2]); acc[3] = fmaf(xv.w, w, acc[3]);
    }
#pragma unroll
    for (int p = 0; p < 4; ++p)
        out[(p0 + ph * 4 + p) * 96 + j] = acc[p];
}

extern "C" void kernel_launch(void* const* d_in, const int* in_sizes, int n_in,
                              void* d_out, int out_size, void* d_ws, size_t ws_size,
                              hipStream_t stream) {
    const float* x      = (const float*)d_in[0];
    const float* W_in   = (const float*)d_in[1];
    const float* conv_w = (const float*)d_in[2];
    const float* conv_b = (const float*)d_in[3];
    const float* W_xproj= (const float*)d_in[4];
    const float* W_dt   = (const float*)d_in[5];
    const float* b_dt   = (const float*)d_in[6];
    const float* A_log  = (const float*)d_in[7];
    const float* D_skip = (const float*)d_in[8];
    const float* W_out  = (const float*)d_in[9];
    float* out = (float*)d_out;

    float* ws   = (float*)d_ws;
    float* xm   = ws;                        // [NPIX*CIN]
    float* z    = xm  + NPIX * CIN;          // [NPIX*CIN]
    float* xcv  = z   + NPIX * CIN;          // (dead; kept for layout stability)
    float2* dtx2= (float2*)(xcv + NPIX * CIN); // [NPIX*CIN] float2
    float* Bp   = (float*)(dtx2 + (size_t)NPIX * CIN); // [NPIX*NST]
    float* Cp   = Bp  + NPIX * NST;          // [NPIX*NST]
    float* Y4   = Cp  + NPIX * NST;          // [4*NPIX*CIN] (d-major slabs)
    float* Sd   = Y4  + (size_t)4 * NPIX * CIN;          // [NCH*8*CIN]
    float* qbuf = Sd  + (size_t)NCH * 8 * CIN;           // [NCH*8*CIN*NST]
    // total ~14.0M floats = 56 MB (ws is 268 MB)

    k_inproj  <<<NPIX / 16, 384, 0, stream>>>(x, W_in, xm, z);
    k_xproj_dt<<<(NPIX + 23) / 24, 512, 0, stream>>>(xm, conv_w, conv_b,
                                                     W_xproj, W_dt, b_dt, Bp, Cp, dtx2);
    k_scan_p1 <<<dim3(NCH, 8, 2), 384, 0, stream>>>(dtx2, Bp, A_log, Sd, qbuf);
    k_scan_fix<<<dim3(12, 8), 256, 0, stream>>>(Sd, A_log, qbuf, NCH);
    k_scan_p2 <<<dim3(NCH, 8, 2), 384, 0, stream>>>(dtx2, Bp, Cp, A_log, D_skip, qbuf, Y4);
    k_gateout <<<NPIX / 16, 384, 0, stream>>>(Y4, z, W_out, out);
}

// Round 10
// 194.133 us; speedup vs baseline: 2.6359x; 1.0907x over previous
//
#include <hip/hip_runtime.h>
#include <math.h>

#define NPIX 6272       // B*H*W = 2*56*56
#define LVAL 3136       // H*W
#define CIN 192         // d_inner
#define NST 16          // d_state
#define HW 56
#define CHUNK 28
#define NCH 112         // LVAL / CHUNK

__device__ __forceinline__ float softplusf(float v) {
    return (v > 20.0f) ? v : log1pf(expf(v));
}

// direction geometry: pixel(l) = off + i*si + j*sj, l = i*56 + j
__device__ __forceinline__ void dir_geom(int d, int b, int& si, int& sj, int& off) {
    if (d == 0)      { si = HW;  sj = 1;   off = b * LVAL; }
    else if (d == 1) { si = HW;  sj = -1;  off = b * LVAL + (HW - 1); }
    else if (d == 2) { si = 1;   sj = HW;  off = b * LVAL; }
    else             { si = -1;  sj = HW;  off = b * LVAL + (HW - 1); }
}

// K1: xz = x @ W_in ; 16 pixels/block, LDS-broadcast x, acc[16]/thread.
// (R2-exact; R9's editing artifact removed.)
__global__ __launch_bounds__(384) void k_inproj(
    const float* __restrict__ x, const float* __restrict__ W_in,
    float* __restrict__ xm, float* __restrict__ z)
{
    __shared__ __align__(16) float xs[96][20];
    const int p0 = blockIdx.x * 16;
    const int t = threadIdx.x;
    for (int e = t; e < 16 * 96; e += 384) {
        int p = e / 96, kk = e % 96;
        xs[kk][p] = x[p0 * 96 + e];
    }
    __syncthreads();
    float acc[16];
#pragma unroll
    for (int p = 0; p < 16; ++p) acc[p] = 0.f;
    for (int k = 0; k < 96; ++k) {
        float w = W_in[k * 384 + t];
        float4 x0 = *(const float4*)&xs[k][0];
        float4 x1 = *(const float4*)&xs[k][4];
        float4 x2 = *(const float4*)&xs[k][8];
        float4 x3 = *(const float4*)&xs[k][12];
        acc[0]  = fmaf(x0.x, w, acc[0]);  acc[1]  = fmaf(x0.y, w, acc[1]);
        acc[2]  = fmaf(x0.z, w, acc[2]);  acc[3]  = fmaf(x0.w, w, acc[3]);
        acc[4]  = fmaf(x1.x, w, acc[4]);  acc[5]  = fmaf(x1.y, w, acc[5]);
        acc[6]  = fmaf(x1.z, w, acc[6]);  acc[7]  = fmaf(x1.w, w, acc[7]);
        acc[8]  = fmaf(x2.x, w, acc[8]);  acc[9]  = fmaf(x2.y, w, acc[9]);
        acc[10] = fmaf(x2.z, w, acc[10]); acc[11] = fmaf(x2.w, w, acc[11]);
        acc[12] = fmaf(x3.x, w, acc[12]); acc[13] = fmaf(x3.y, w, acc[13]);
        acc[14] = fmaf(x3.z, w, acc[14]); acc[15] = fmaf(x3.w, w, acc[15]);
    }
#pragma unroll
    for (int p = 0; p < 16; ++p) {
        int pix = p0 + p;
        if (t < 192) xm[pix * CIN + t] = acc[p];
        else         z[pix * CIN + (t - 192)] = acc[p];
    }
}

// K2: depthwise 3x3 conv, pad 1 — float4 over channels (4 ch/thread).
// (Separate kernel RESTORED — R9's fusion ran 1 block/CU with scalar 9x
// amplified reads and regressed; this spreads the same traffic over 1176
// blocks with float4 loads.)
__global__ __launch_bounds__(256) void k_conv(
    const float* __restrict__ xm, const float* __restrict__ cw,
    const float* __restrict__ cb, float* __restrict__ xcv)
{
    int e = blockIdx.x * 256 + threadIdx.x;          // (pix, c-quad)
    if (e >= NPIX * (CIN / 4)) return;
    int cq = (e % (CIN / 4)) * 4;
    int pix = e / (CIN / 4);
    int w = pix % HW;
    int rest = pix / HW;
    int h = rest % HW;
    int b = rest / HW;
    float4 acc = *(const float4*)&cb[cq];
#pragma unroll
    for (int ky = 0; ky < 3; ++ky) {
        int hh = h + ky - 1;
        if (hh < 0 || hh >= HW) continue;
#pragma unroll
        for (int kx = 0; kx < 3; ++kx) {
            int ww = w + kx - 1;
            if (ww < 0 || ww >= HW) continue;
            float4 xv = *(const float4*)&xm[((b * HW + hh) * HW + ww) * CIN + cq];
            float4 wv = *(const float4*)&cw[(ky * 3 + kx) * CIN + cq];
            acc.x = fmaf(xv.x, wv.x, acc.x);
            acc.y = fmaf(xv.y, wv.y, acc.y);
            acc.z = fmaf(xv.z, wv.z, acc.z);
            acc.w = fmaf(xv.w, wv.w, acc.w);
        }
    }
    *(float4*)&xcv[pix * CIN + cq] = acc;
}

// K3: fused xproj + dt, K-SPLIT (R2-exact, reads xcv).
__global__ __launch_bounds__(512) void k_xproj_dt(
    const float* __restrict__ xcv, const float* __restrict__ W_xproj,
    const float* __restrict__ W_dt, const float* __restrict__ b_dt,
    float* __restrict__ Bp, float* __restrict__ Cp, float2* __restrict__ dtx2)
{
    __shared__ __align__(16) float xs[192][28];
    __shared__ float part[2][24][40];
    __shared__ float dtr_lds[24][8];
    const int p0 = blockIdx.x * 24;
    const int t = threadIdx.x;
    for (int e = t; e < 24 * 192; e += 512) {
        int p = e / 192, kk = e % 192;
        int pix = p0 + p;
        xs[kk][p] = (pix < NPIX) ? xcv[pix * CIN + kk] : 0.f;
    }
    __syncthreads();
    const int th = t & 255;
    const int kh = t >> 8;               // 0..1 -> k range [kh*96, kh*96+96)
    const int j  = th % 40;
    const int pq = th / 40;              // 0..6; pq==6 idle
    if (pq < 6) {
        const int jc = (j < 38) ? j : 37;
        float a0 = 0.f, a1 = 0.f, a2 = 0.f, a3 = 0.f;
        const int k0 = kh * 96;
        for (int k = k0; k < k0 + 96; ++k) {
            float w = W_xproj[k * 38 + jc];
            float4 xv = *(const float4*)&xs[k][pq * 4];
            a0 = fmaf(xv.x, w, a0); a1 = fmaf(xv.y, w, a1);
            a2 = fmaf(xv.z, w, a2); a3 = fmaf(xv.w, w, a3);
        }
        part[kh][pq * 4 + 0][j] = a0;
        part[kh][pq * 4 + 1][j] = a1;
        part[kh][pq * 4 + 2][j] = a2;
        part[kh][pq * 4 + 3][j] = a3;
    }
    __syncthreads();
    if (kh == 0 && pq < 6 && j < 38) {
#pragma unroll
        for (int q = 0; q < 4; ++q) {
            int p = pq * 4 + q;
            float r = part[0][p][j] + part[1][p][j];
            int pix = p0 + p;
            if (j < 6) dtr_lds[p][j] = r;
            if (pix < NPIX) {
                if (j < 6)       ;   // dtr stays in LDS
                else if (j < 22) Bp[pix * NST + (j - 6)] = r;
                else             Cp[pix * NST + (j - 22)] = r;
            }
        }
    }
    __syncthreads();
    // Phase B: dt = softplus(dtr@W_dt + b_dt); pack with x from LDS.
    for (int e = t; e < 24 * 192; e += 512) {
        int p = e / 192, c = e % 192;
        int pix = p0 + p;
        if (pix >= NPIX) continue;
        float v = b_dt[c];
#pragma unroll
        for (int r = 0; r < 6; ++r)
            v = fmaf(dtr_lds[p][r], W_dt[r * CIN + c], v);
        dtx2[(size_t)pix * CIN + c] = make_float2(softplusf(v), xs[c][p]);
    }
}

// K4a pass1 — R2 geometry (4-way n-split, grid (112,8,2)).
// ONLY change vs R2: store Sdt (scalar per channel) instead of P (float4);
// k_scan_fix recomputes P = exp2(a2*Sdt) with the identical formula ->
// bit-identical results, ~21 MB less traffic.
__global__ __launch_bounds__(384) void k_scan_p1(
    const float2* __restrict__ dtx2, const float* __restrict__ Bp,
    const float* __restrict__ A_log,
    float* __restrict__ Sd, float* __restrict__ qbuf)
{
    constexpr int CPR = HW / CHUNK;
    __shared__ __align__(16) float Bs[CHUNK * NST];
    const int g = blockIdx.y;
    const int k = blockIdx.x;
    const int ch = blockIdx.z;           // channel half: [ch*96, ch*96+96)
    const int t = threadIdx.x;
    const int wv = t >> 6;
    const int lane = t & 63;
    const int cl = lane & 15, nh = lane >> 4;   // 16 channels x 4 n-groups
    const int c = ch * 96 + wv * 16 + cl;
    const int n0 = nh * 4;
    const int d = g >> 1, b = g & 1;
    int si, sj, off;
    dir_geom(d, b, si, sj, off);
    const int base = off + (k / CPR) * si + ((k % CPR) * CHUNK) * sj;

    for (int e = t; e < CHUNK * NST; e += 384) {
        int jj = e >> 4, n = e & 15;
        Bs[e] = Bp[(base + jj * sj) * NST + n];
    }

    const float LOG2E = 1.4426950408889634f;
    float a2[4];
    {
        float4 v = *(const float4*)(A_log + c * NST + n0);
        a2[0] = -expf(v.x) * LOG2E;
        a2[1] = -expf(v.y) * LOG2E;
        a2[2] = -expf(v.z) * LOG2E;
        a2[3] = -expf(v.w) * LOG2E;
    }
    __syncthreads();

    float h[4];
#pragma unroll
    for (int i = 0; i < 4; ++i) h[i] = 0.f;
    float Sdt = 0.f;

    const float2* dp = dtx2 + (size_t)base * CIN + c;
    const ptrdiff_t dstep = (ptrdiff_t)sj * CIN;

#define P1_STEP(DVV, JJ) do {                                            \
        float dt_c = (DVV).x, x_c = (DVV).y;                             \
        float dtx = dt_c * x_c;                                          \
        Sdt += dt_c;                                                     \
        float4 t0 = *(const float4*)(Bs + (JJ) * NST + n0);              \
        float Bv[4] = {t0.x, t0.y, t0.z, t0.w};                          \
        _Pragma("unroll")                                                \
        for (int i = 0; i < 4; ++i) {                                    \
            float dA = exp2f(dt_c * a2[i]);                              \
            h[i] = fmaf(dA, h[i], dtx * Bv[i]);                          \
        }                                                                \
    } while (0)

    float2 v0 = dp[0];
    float2 v1 = dp[dstep];
    float2 v2 = dp[2 * dstep];
    float2 v3 = dp[3 * dstep];
    for (int jj = 0; jj < CHUNK; jj += 4) {
        const int j4 = (jj + 4 < CHUNK) ? jj + 4 : CHUNK - 4;
        float2 nv0 = dp[(ptrdiff_t)(j4 + 0) * dstep];
        float2 nv1 = dp[(ptrdiff_t)(j4 + 1) * dstep];
        float2 nv2 = dp[(ptrdiff_t)(j4 + 2) * dstep];
        float2 nv3 = dp[(ptrdiff_t)(j4 + 3) * dstep];
        P1_STEP(v0, jj + 0);
        P1_STEP(v1, jj + 1);
        P1_STEP(v2, jj + 2);
        P1_STEP(v3, jj + 3);
        v0 = nv0; v1 = nv1; v2 = nv2; v3 = nv3;
    }
#undef P1_STEP

    if (nh == 0)
        Sd[(size_t)(k * 8 + g) * CIN + c] = Sdt;   // shared across n-groups
    float4* qd = (float4*)(qbuf + ((size_t)(k * 8 + g) * CIN + c) * NST + n0);
    qd[0] = make_float4(h[0], h[1], h[2], h[3]);
}

// K4b: sequential chunk combine. P recomputed from Sdt + A_log inline
// (identical -expf(A_log)*LOG2E formula as p1 -> bit-identical P).
__global__ __launch_bounds__(256) void k_scan_fix(
    const float* __restrict__ Sd, const float* __restrict__ A_log,
    float* __restrict__ qbuf, int nch)
{
    const int g = blockIdx.y;
    const int lo = blockIdx.x * 256 + threadIdx.x;   // 0..3071 = c*16+n
    const int c = lo >> 4;
    const float LOG2E = 1.4426950408889634f;
    const float a2t = -expf(A_log[lo]) * LOG2E;
    const size_t stride = (size_t)8 * CIN * NST;
    const size_t sstride = (size_t)8 * CIN;
    size_t idx  = (size_t)g * CIN * NST + lo;
    size_t pidx = idx;
    size_t sidx = (size_t)g * CIN + c;
    float Sv[8], qr[8];
#pragma unroll
    for (int i = 0; i < 8; ++i) {
        Sv[i] = Sd[sidx]; qr[i] = qbuf[pidx];
        sidx += sstride; pidx += stride;
    }
    float h = 0.f;
    for (int k = 0; k < nch; k += 8) {
        float Sn[8], qn[8];
        if (k + 8 < nch) {
#pragma unroll
            for (int i = 0; i < 8; ++i) {
                Sn[i] = Sd[sidx + (size_t)i * sstride];
                qn[i] = qbuf[pidx + (size_t)i * stride];
            }
        } else {
#pragma unroll
            for (int i = 0; i < 8; ++i) { Sn[i] = 0.f; qn[i] = 0.f; }
        }
#pragma unroll
        for (int i = 0; i < 8; ++i) {
            qbuf[idx] = h;
            float P = exp2f(a2t * Sv[i]);
            h = fmaf(P, h, qr[i]);
            idx += stride;
        }
#pragma unroll
        for (int i = 0; i < 8; ++i) { Sv[i] = Sn[i]; qr[i] = qn[i]; }
        sidx += (size_t)8 * sstride;
        pidx += (size_t)8 * stride;
    }
}

// K4c pass2 — R2-exact: 4-way n-split; y via shfl_xor(16)+shfl_xor(32).
__global__ __launch_bounds__(384) void k_scan_p2(
    const float2* __restrict__ dtx2, const float* __restrict__ Bp,
    const float* __restrict__ Cp, const float* __restrict__ A_log,
    const float* __restrict__ D_skip,
    const float* __restrict__ qbuf, float* __restrict__ Y4)
{
    constexpr int CPR = HW / CHUNK;
    __shared__ __align__(16) float Bs[CHUNK * NST];
    __shared__ __align__(16) float Cs[CHUNK * NST];
    const int g = blockIdx.y;
    const int k = blockIdx.x;
    const int ch = blockIdx.z;
    const int t = threadIdx.x;
    const int wv = t >> 6;
    const int lane = t & 63;
    const int cl = lane & 15, nh = lane >> 4;
    const int c = ch * 96 + wv * 16 + cl;
    const int n0 = nh * 4;
    const int d = g >> 1, b = g & 1;
    int si, sj, off;
    dir_geom(d, b, si, sj, off);
    const int base = off + (k / CPR) * si + ((k % CPR) * CHUNK) * sj;

    for (int e = t; e < CHUNK * NST; e += 384) {
        int jj = e >> 4, n = e & 15;
        int pa = (base + jj * sj) * NST + n;
        Bs[e] = Bp[pa];
        Cs[e] = Cp[pa];
    }

    const float LOG2E = 1.4426950408889634f;
    float a2[4];
    {
        float4 v = *(const float4*)(A_log + c * NST + n0);
        a2[0] = -expf(v.x) * LOG2E;
        a2[1] = -expf(v.y) * LOG2E;
        a2[2] = -expf(v.z) * LOG2E;
        a2[3] = -expf(v.w) * LOG2E;
    }
    const float Dc = D_skip[c];

    float h[4];
    {
        float4 v0q = *(const float4*)(qbuf + ((size_t)(k * 8 + g) * CIN + c) * NST + n0);
        h[0]=v0q.x; h[1]=v0q.y; h[2]=v0q.z; h[3]=v0q.w;
    }
    __syncthreads();

    float* yo = Y4 + ((size_t)d * NPIX + (size_t)b * LVAL + (size_t)k * CHUNK) * CIN;

    const float2* dp = dtx2 + (size_t)base * CIN + c;
    const ptrdiff_t dstep = (ptrdiff_t)sj * CIN;

#define P2_STEP(DVV, JJ) do {                                            \
        float dt_c = (DVV).x, x_c = (DVV).y;                             \
        float dtx = dt_c * x_c;                                          \
        float4 t0 = *(const float4*)(Bs + (JJ) * NST + n0);              \
        float4 u0 = *(const float4*)(Cs + (JJ) * NST + n0);              \
        float Bv[4] = {t0.x, t0.y, t0.z, t0.w};                          \
        float Cv[4] = {u0.x, u0.y, u0.z, u0.w};                          \
        float yc0 = 0.f, yc1 = 0.f;                                      \
        _Pragma("unroll")                                                \
        for (int i = 0; i < 4; i += 2) {                                 \
            float dA0 = exp2f(dt_c * a2[i]);                             \
            float dA1 = exp2f(dt_c * a2[i+1]);                           \
            h[i]   = fmaf(dA0, h[i],   dtx * Bv[i]);                     \
            h[i+1] = fmaf(dA1, h[i+1], dtx * Bv[i+1]);                   \
            yc0 = fmaf(h[i],   Cv[i],   yc0);                            \
            yc1 = fmaf(h[i+1], Cv[i+1], yc1);                            \
        }                                                                \
        float yc = yc0 + yc1;                                            \
        yc += __shfl_xor(yc, 16, 64);                                    \
        yc += __shfl_xor(yc, 32, 64);                                    \
        if (nh == 0)                                                     \
            yo[(JJ) * CIN + c] = fmaf(Dc, x_c, yc);                      \
    } while (0)

    float2 v0 = dp[0];
    float2 v1 = dp[dstep];
    float2 v2 = dp[2 * dstep];
    float2 v3 = dp[3 * dstep];
    for (int jj = 0; jj < CHUNK; jj += 4) {
        const int j4 = (jj + 4 < CHUNK) ? jj + 4 : CHUNK - 4;
        float2 nv0 = dp[(ptrdiff_t)(j4 + 0) * dstep];
        float2 nv1 = dp[(ptrdiff_t)(j4 + 1) * dstep];
        float2 nv2 = dp[(ptrdiff_t)(j4 + 2) * dstep];
        float2 nv3 = dp[(ptrdiff_t)(j4 + 3) * dstep];
        P2_STEP(v0, jj + 0);
        P2_STEP(v1, jj + 1);
        P2_STEP(v2, jj + 2);
        P2_STEP(v3, jj + 3);
        v0 = nv0; v1 = nv1; v2 = nv2; v3 = nv3;
    }
#undef P2_STEP
}

// K5: fused gate + outproj. 16 pixels/block, 384 threads, acc[4]/thread.
__global__ __launch_bounds__(384) void k_gateout(
    const float* __restrict__ Y4, const float* __restrict__ z,
    const float* __restrict__ W_out, float* __restrict__ out)
{
    __shared__ __align__(16) float xs[192][20];
    const int p0 = blockIdx.x * 16;
    const int t = threadIdx.x;
    const size_t NP = (size_t)NPIX * CIN;
    for (int e = t; e < 16 * 192; e += 384) {
        int p = e / 192, c = e % 192;
        size_t idx = (size_t)(p0 + p) * CIN + c;
        float s = Y4[idx] + Y4[idx + NP] + Y4[idx + 2 * NP] + Y4[idx + 3 * NP];
        float zz = z[idx];
        float sig = 1.f / (1.f + expf(-zz));
        xs[c][p] = zz * sig * s;
    }
    __syncthreads();
    const int j  = t % 96;
    const int ph = t / 96;          // 0..3 -> pixels ph*4 .. ph*4+3
    float acc[4] = {0.f, 0.f, 0.f, 0.f};
    for (int k = 0; k < 192; ++k) {
        float w = W_out[k * 96 + j];
        float4 xv = *(const float4*)&xs[k][ph * 4];
        acc[0] = fmaf(xv.x, w, acc[0]); acc[1] = fmaf(xv.y, w, acc[1]);
        acc[2] = fmaf(xv.z, w, acc[2]); acc[3] = fmaf(xv.w, w, acc[3]);
    }
#pragma unroll
    for (int p = 0; p < 4; ++p)
        out[(p0 + ph * 4 + p) * 96 + j] = acc[p];
}

extern "C" void kernel_launch(void* const* d_in, const int* in_sizes, int n_in,
                              void* d_out, int out_size, void* d_ws, size_t ws_size,
                              hipStream_t stream) {
    const float* x      = (const float*)d_in[0];
    const float* W_in   = (const float*)d_in[1];
    const float* conv_w = (const float*)d_in[2];
    const float* conv_b = (const float*)d_in[3];
    const float* W_xproj= (const float*)d_in[4];
    const float* W_dt   = (const float*)d_in[5];
    const float* b_dt   = (const float*)d_in[6];
    const float* A_log  = (const float*)d_in[7];
    const float* D_skip = (const float*)d_in[8];
    const float* W_out  = (const float*)d_in[9];
    float* out = (float*)d_out;

    float* ws   = (float*)d_ws;
    float* xm   = ws;                        // [NPIX*CIN]
    float* z    = xm  + NPIX * CIN;          // [NPIX*CIN]
    float* xcv  = z   + NPIX * CIN;          // [NPIX*CIN]
    float2* dtx2= (float2*)(xcv + NPIX * CIN); // [NPIX*CIN] float2
    float* Bp   = (float*)(dtx2 + (size_t)NPIX * CIN); // [NPIX*NST]
    float* Cp   = Bp  + NPIX * NST;          // [NPIX*NST]
    float* Y4   = Cp  + NPIX * NST;          // [4*NPIX*CIN] (d-major slabs)
    float* Sd   = Y4  + (size_t)4 * NPIX * CIN;          // [NCH*8*CIN]
    float* qbuf = Sd  + (size_t)NCH * 8 * CIN;           // [NCH*8*CIN*NST]
    // total ~14.2M floats = 57 MB (ws is 268 MB)

    k_inproj  <<<NPIX / 16, 384, 0, stream>>>(x, W_in, xm, z);
    k_conv    <<<(NPIX * (CIN / 4)) / 256, 256, 0, stream>>>(xm, conv_w, conv_b, xcv);
    k_xproj_dt<<<(NPIX + 23) / 24, 512, 0, stream>>>(xcv, W_xproj, W_dt, b_dt, Bp, Cp, dtx2);
    k_scan_p1 <<<dim3(NCH, 8, 2), 384, 0, stream>>>(dtx2, Bp, A_log, Sd, qbuf);
    k_scan_fix<<<dim3(12, 8), 256, 0, stream>>>(Sd, A_log, qbuf, NCH);
    k_scan_p2 <<<dim3(NCH, 8, 2), 384, 0, stream>>>(dtx2, Bp, Cp, A_log, D_skip, qbuf, Y4);
    k_gateout <<<NPIX / 16, 384, 0, stream>>>(Y4, z, W_out, out);
}